// Round 6
// baseline (937.527 us; speedup 1.0000x reference)
//
#include <hip/hip_runtime.h>
#include <stdint.h>

// Problem constants (fixed by the reference file)
#define BATCH   8
#define C_OUT_N 96
#define NK      11
#define C_IN_N  1056      // C_OUT_N * NK
#define GRP     4
#define HOUT    56
#define WOUT    56
#define HIN     60
#define WIN     60
#define EP      2
#define NELEM   (HIN * WIN)        // 3600 dwords = 14400 B per channel

// s_waitcnt imm (gfx9): vmcnt[3:0] | expcnt(7)<<4 | lgkmcnt(15)<<8  (no lgkm/exp wait)
#define WAITCNT_VM(n) __builtin_amdgcn_s_waitcnt(0x0F70 | (n))

__device__ __forceinline__ void gl_lds16(const void* g, void* l) {
    __builtin_amdgcn_global_load_lds(
        (const __attribute__((address_space(1))) void*)g,
        (__attribute__((address_space(3))) void*)l, 16, 0, 0);
}

// Stage one 14400B channel into LDS: 16 x (64 lanes x 16B) = wave-uniform dest.
// t=0..13 cover [0,14336); t=14,15 cover [13376,14400) (overlapped tail, always
// in-bounds for every channel). Wave wv issues t = 4*wv .. 4*wv+3.
__device__ __forceinline__ void stage_channel(const float* chan, float* buf,
                                              int wv, int lane) {
#pragma unroll
    for (int j = 0; j < 4; ++j) {
        const int t = wv * 4 + j;
        const int off = (t <= 13) ? t * 1024 : 13376;   // bytes, 16B-aligned
        gl_lds16((const char*)chan + off + lane * 16, (char*)buf + off);
    }
}

// One block per (b, co); 4 waves; wave wv owns output rows wv*14 .. wv*14+13.
__global__ __launch_bounds__(256) void addshift_kernel(
    const float* __restrict__ x,
    const float* __restrict__ w1,
    const float* __restrict__ w2,
    const float* __restrict__ w3,
    const int*   __restrict__ pad_hv,       // (C_IN, 8)
    const int*   __restrict__ idx_identit,  // (C_OUT, 4)
    float* __restrict__ out)                // [out_h | out_v | out_i]
{
    const int co   = blockIdx.x;
    const int b    = blockIdx.y;
    const int tid  = threadIdx.x;
    const int wv   = tid >> 6;
    const int lane = tid & 63;

    __shared__ __align__(16) float tile[2][NELEM];   // 2 x 14400 B

    const float* chan_base = x + ((size_t)b * C_IN_N + (size_t)co * NK) * NELEM;

    const int h0   = wv * 14;
    const int colc = (lane + EP < WIN) ? (lane + EP) : (WIN - 1);  // clamp idle lanes

    // Block-uniform identity-gather info
    int   kIg[GRP];
    float w3v[GRP];
#pragma unroll
    for (int g = 0; g < GRP; ++g) {
        kIg[g] = idx_identit[co * GRP + g] - co * NK;   // in [0, NK)
        w3v[g] = w3[g * C_OUT_N + co];
    }

    float accH[14], accV[14], accI[14];
#pragma unroll
    for (int i = 0; i < 14; ++i) { accH[i] = 0.f; accV[i] = 0.f; accI[i] = 0.f; }

    // Prologue: stage channel 0 into buf0
    stage_channel(chan_base, tile[0], wv, lane);

#pragma unroll
    for (int k = 0; k < NK; ++k) {
        // Issue next channel's loads into the other buffer (stay in flight)
        if (k < NK - 1)
            stage_channel(chan_base + (size_t)(k + 1) * NELEM, tile[(k + 1) & 1], wv, lane);
        // Wait only for channel k's 4 loads (the older ones); k+1's 4 remain outstanding
        if (k < NK - 1) WAITCNT_VM(4); else WAITCNT_VM(0);
        __builtin_amdgcn_s_barrier();    // raw: no compiler vmcnt(0) drain

        const float* tb = tile[k & 1];
        const int c = co * NK + k;

#pragma unroll
        for (int g = 0; g < GRP; ++g) {
            const int   ph = pad_hv[c * 8 + g];          // block-uniform -> s_load
            const int   pv = pad_hv[c * 8 + 4 + g];
            const float a1 = w1[g * C_IN_N + c];
            const float a2 = w2[g * C_IN_N + c];

            // H: per-lane column shift; clamp col + zero weight when OOB
            const int  iw  = lane + EP + ph;
            const bool vHm = (unsigned)iw < (unsigned)WIN;
            const int  iwc = vHm ? iw : 0;
            const float a1m = vHm ? a1 : 0.f;

#pragma unroll
            for (int i = 0; i < 14; ++i) {
                accH[i] = fmaf(tb[(h0 + i + EP) * WIN + iwc], a1m, accH[i]);
                // V: per-i row shift; clamp row + zero weight when OOB
                const int  ih  = h0 + i + EP + pv;
                const bool vVm = (unsigned)ih < (unsigned)HIN;
                accV[i] = fmaf(tb[(vVm ? ih : 0) * WIN + colc], vVm ? a2 : 0.f, accV[i]);
            }
        }

        // Identity term: channels matching this k (block-uniform)
        float wi = 0.f;
#pragma unroll
        for (int g = 0; g < GRP; ++g)
            if (kIg[g] == k) wi += w3v[g];
        if (wi != 0.f) {
#pragma unroll
            for (int i = 0; i < 14; ++i)
                accI[i] = fmaf(tb[(h0 + i + EP) * WIN + colc], wi, accI[i]);
        }

        __builtin_amdgcn_s_barrier();    // all waves done with tb before it's reloaded
    }

    // Epilogue: dense scalar stores (R1-proven write pattern)
    if (lane < WOUT) {
        const size_t OSZ  = (size_t)BATCH * C_OUT_N * HOUT * WOUT;
        const size_t base = (((size_t)b * C_OUT_N + co) * HOUT + h0) * WOUT + lane;
#pragma unroll
        for (int i = 0; i < 14; ++i) {
            out[base + (size_t)i * WOUT]           = accH[i];
            out[OSZ + base + (size_t)i * WOUT]     = accV[i];
            out[2 * OSZ + base + (size_t)i * WOUT] = accI[i];
        }
    }
}

extern "C" void kernel_launch(void* const* d_in, const int* in_sizes, int n_in,
                              void* d_out, int out_size, void* d_ws, size_t ws_size,
                              hipStream_t stream) {
    const float* x   = (const float*)d_in[0];
    const float* w1  = (const float*)d_in[1];
    const float* w2  = (const float*)d_in[2];
    const float* w3  = (const float*)d_in[3];
    const int* pad_hv      = (const int*)d_in[4];
    const int* idx_identit = (const int*)d_in[5];
    float* out = (float*)d_out;

    dim3 grid(C_OUT_N, BATCH);   // 768 blocks; LDS 28.8KB + ~no VGPR cap -> ~5 blocks/CU capacity
    dim3 block(256);
    addshift_kernel<<<grid, block, 0, stream>>>(x, w1, w2, w3, pad_hv, idx_identit, out);
}

// Round 7
// 360.507 us; speedup vs baseline: 2.6006x; 2.6006x over previous
//
#include <hip/hip_runtime.h>

// Problem constants (fixed by the reference file)
#define BATCH   8
#define C_OUT_N 96
#define NK      11
#define C_IN_N  1056      // C_OUT_N * NK
#define GRP     4
#define HOUT    56
#define WOUT    56
#define HIN     60
#define WIN     60
#define EP      2
#define NELEM   (HIN * WIN)     // 3600 dwords per channel

// Row-major LDS tile, rows zero-padded for vertical OOB (ih in [-27,78]):
// tile[(row + RPAD)*STR + col], interior is LINEAR (STR == WIN) so staging is
// a straight copy. Columns are NOT padded: H handles OOB by clamp + weight-zero.
#define RPAD    27
#define RBOT    19               // rows 60..78
#define RTOT    (RPAD + HIN + RBOT)   // 106
#define STR     WIN              // 60 dwords
#define TILE_DW (RTOT * STR)     // 6360 dwords = 25440 B
#define INT0    (RPAD * STR)     // 1620, interior start (16B aligned)

typedef float fvec4 __attribute__((ext_vector_type(4)));

// One block per (b, co); 4 waves; wave wv owns output rows wv*14 .. wv*14+13.
// __launch_bounds__(256,4): VGPR cap 128 (need ~90) -> no spill, >=4 blocks/CU.
__global__ __launch_bounds__(256, 4) void addshift_kernel(
    const float* __restrict__ x,
    const float* __restrict__ w1,
    const float* __restrict__ w2,
    const float* __restrict__ w3,
    const int*   __restrict__ pad_hv,       // (C_IN, 8)
    const int*   __restrict__ idx_identit,  // (C_OUT, 4)
    float* __restrict__ out)                // [out_h | out_v | out_i]
{
    const int co   = blockIdx.x;
    const int b    = blockIdx.y;
    const int tid  = threadIdx.x;
    const int wv   = tid >> 6;
    const int lane = tid & 63;

    __shared__ __align__(16) float tile[TILE_DW];

    // One-time zero of pad rows (top 27 rows = 405 fvec4; bottom 19 rows = 285 fvec4)
    {
        const fvec4 z4 = {0.f, 0.f, 0.f, 0.f};
        for (int j = tid; j < 405; j += 256) ((fvec4*)tile)[j] = z4;
        for (int j = tid; j < 285; j += 256) ((fvec4*)tile)[(INT0 + HIN * STR) / 4 + j] = z4;
    }

    // Block-uniform identity-gather info
    int   kIg[GRP];
    float w3v[GRP];
#pragma unroll
    for (int g = 0; g < GRP; ++g) {
        kIg[g] = idx_identit[co * GRP + g] - co * NK;   // in [0, NK)
        w3v[g] = w3[g * C_OUT_N + co];
    }

    float accH[14], accV[14], accI[14];
#pragma unroll
    for (int i = 0; i < 14; ++i) { accH[i] = 0.f; accV[i] = 0.f; accI[i] = 0.f; }

    const float* chan_base = x + ((size_t)b * C_IN_N + (size_t)co * NK) * NELEM;

    const int h0   = wv * 14;
    const int colc = (lane + EP < WIN) ? (lane + EP) : (WIN - 1);  // clamp idle lanes

    // Prologue: prefetch channel 0 (900 fvec4 across 256 threads)
    fvec4 pre[4];
    {
        const fvec4* src4 = (const fvec4*)chan_base;
#pragma unroll
        for (int t = 0; t < 4; ++t) {
            int j = tid + t * 256;
            pre[t] = src4[j < 900 ? j : 899];
        }
    }

    __syncthreads();   // pad-clear visible before first compute

#pragma unroll 1
    for (int k = 0; k < NK; ++k) {
        // regs -> LDS interior (linear copy; 16B-aligned: INT0%4==0)
#pragma unroll
        for (int t = 0; t < 4; ++t) {
            int j = tid + t * 256;
            if (j < 900) *(fvec4*)&tile[INT0 + j * 4] = pre[t];
        }
        __syncthreads();

        // Prefetch next channel while this one computes
        if (k < NK - 1) {
            const fvec4* src4 = (const fvec4*)(chan_base + (size_t)(k + 1) * NELEM);
#pragma unroll
            for (int t = 0; t < 4; ++t) {
                int j = tid + t * 256;
                pre[t] = src4[j < 900 ? j : 899];
            }
        }

        const int c = co * NK + k;
        // Block-uniform per-channel shifts & weights (scalar loads)
        int ph[GRP], pv[GRP];
        float a1[GRP], a2[GRP];
#pragma unroll
        for (int g = 0; g < GRP; ++g) {
            ph[g] = pad_hv[c * 8 + g];
            pv[g] = pad_hv[c * 8 + 4 + g];
            a1[g] = w1[g * C_IN_N + c];
            a2[g] = w2[g * C_IN_N + c];
        }
        float wi = 0.f;
#pragma unroll
        for (int g = 0; g < GRP; ++g)
            if (kIg[g] == k) wi += w3v[g];

#pragma unroll
        for (int g = 0; g < GRP; ++g) {
            // H: per-lane column shift; clamp col + zero weight when OOB
            const int  iw  = lane + EP + ph[g];
            const bool vH  = (unsigned)iw < (unsigned)WIN;
            const int  iwc = vH ? iw : 0;
            const float a1m = vH ? a1[g] : 0.f;
            const int offH = (RPAD + h0 + EP) * STR + iwc;          // +i*STR
            // V: row shift absorbed by zero pad rows (always in-bounds)
            const int offV = (RPAD + h0 + EP + pv[g]) * STR + colc; // +i*STR
#pragma unroll
            for (int i = 0; i < 14; ++i) {
                accH[i] = fmaf(tile[offH + i * STR], a1m, accH[i]);
                accV[i] = fmaf(tile[offV + i * STR], a2[g], accV[i]);
            }
        }
        if (wi != 0.f) {                 // block-uniform branch
            const int offI = (RPAD + h0 + EP) * STR + colc;
#pragma unroll
            for (int i = 0; i < 14; ++i)
                accI[i] = fmaf(tile[offI + i * STR], wi, accI[i]);
        }
        __syncthreads();   // all waves done with tile before next k's staging
    }

    // Epilogue: dense scalar stores (R1-proven write pattern)
    if (lane < WOUT) {
        const size_t OSZ  = (size_t)BATCH * C_OUT_N * HOUT * WOUT;
        const size_t base = (((size_t)b * C_OUT_N + co) * HOUT + h0) * WOUT + lane;
#pragma unroll
        for (int i = 0; i < 14; ++i) {
            out[base + (size_t)i * WOUT]           = accH[i];
            out[OSZ + base + (size_t)i * WOUT]     = accV[i];
            out[2 * OSZ + base + (size_t)i * WOUT] = accI[i];
        }
    }
}

extern "C" void kernel_launch(void* const* d_in, const int* in_sizes, int n_in,
                              void* d_out, int out_size, void* d_ws, size_t ws_size,
                              hipStream_t stream) {
    const float* x   = (const float*)d_in[0];
    const float* w1  = (const float*)d_in[1];
    const float* w2  = (const float*)d_in[2];
    const float* w3  = (const float*)d_in[3];
    const int* pad_hv      = (const int*)d_in[4];
    const int* idx_identit = (const int*)d_in[5];
    float* out = (float*)d_out;

    dim3 grid(C_OUT_N, BATCH);   // 768 blocks; LDS 25.4KB + VGPR<=128 -> ~4-6 blocks/CU
    dim3 block(256);
    addshift_kernel<<<grid, block, 0, stream>>>(x, w1, w2, w3, pad_hv, idx_identit, out);
}